// Round 1
// baseline (224.321 us; speedup 1.0000x reference)
//
#include <hip/hip_runtime.h>
#include <hip/hip_bf16.h>

#define BB 8
#define NN 512
#define DINC 128
#define DOUTC 128
#define HHC 8
#define EEC 16
#define DHC 16

typedef __hip_bfloat16 bf16;

__device__ __forceinline__ float wsum(float v){
#pragma unroll
  for (int o=1;o<64;o<<=1) v += __shfl_xor(v,o);
  return v;
}
__device__ __forceinline__ float wmax(float v){
#pragma unroll
  for (int o=1;o<64;o<<=1) v = fmaxf(v,__shfl_xor(v,o));
  return v;
}

// ---------- LN1 + Wp + Q/K/V projections: 8 rows per 128-thread block ----------
__global__ __launch_bounds__(128) void k_proj(
    const float* __restrict__ x,
    const float* __restrict__ g1, const float* __restrict__ b1,
    const float* __restrict__ Wp, const float* __restrict__ bp,
    const float* __restrict__ Wq, const float* __restrict__ Wk, const float* __restrict__ Wv,
    float* __restrict__ xp, float* __restrict__ Qb, float* __restrict__ Kb, float* __restrict__ Vb)
{
  const int R = 8, P = 12;                 // P=12 pad: 48B rows, float4-aligned
  __shared__ float xln[DINC*P];
  __shared__ float xps[DINC*P];
  __shared__ float part[2][R][2];
  int tid = threadIdx.x, w = tid>>6, lane = tid&63;
  int row0 = blockIdx.x * R;
  float v[R];
#pragma unroll
  for (int r=0;r<R;++r) v[r] = x[(size_t)(row0+r)*DINC + tid];
  float gg = g1[tid], bbv = b1[tid];
#pragma unroll
  for (int r=0;r<R;++r){
    float s = wsum(v[r]);
    float q = wsum(v[r]*v[r]);
    if (lane==0){ part[w][r][0]=s; part[w][r][1]=q; }
  }
  __syncthreads();
#pragma unroll
  for (int r=0;r<R;++r){
    float s = part[0][r][0]+part[1][r][0];
    float q = part[0][r][1]+part[1][r][1];
    float mean = s*(1.f/DINC);
    float var  = q*(1.f/DINC) - mean*mean;
    float rstd = rsqrtf(var + 1e-5f);
    xln[tid*P + r] = (v[r]-mean)*rstd*gg + bbv;
  }
  __syncthreads();
  int j = tid;
  float acc[R];
  { // xp = xln @ Wp + bp
    float bj = bp[j];
#pragma unroll
    for (int r=0;r<R;++r) acc[r]=bj;
    for (int i=0;i<DINC;++i){
      float wv = Wp[i*DOUTC + j];
      const float4* xa = (const float4*)&xln[i*P];
      float4 a = xa[0], b = xa[1];
      acc[0]+=a.x*wv; acc[1]+=a.y*wv; acc[2]+=a.z*wv; acc[3]+=a.w*wv;
      acc[4]+=b.x*wv; acc[5]+=b.y*wv; acc[6]+=b.z*wv; acc[7]+=b.w*wv;
    }
#pragma unroll
    for (int r=0;r<R;++r){
      xps[j*P + r] = acc[r];
      xp[(size_t)(row0+r)*DOUTC + j] = acc[r];
    }
  }
  __syncthreads();
  const float* Ws[3] = {Wq, Wk, Wv};
  float* Os[3] = {Qb, Kb, Vb};
#pragma unroll
  for (int mmat=0;mmat<3;++mmat){
    const float* W = Ws[mmat];
#pragma unroll
    for (int r=0;r<R;++r) acc[r]=0.f;
    for (int i=0;i<DINC;++i){
      float wv = W[i*DOUTC + j];
      const float4* xa = (const float4*)&xps[i*P];
      float4 a = xa[0], b = xa[1];
      acc[0]+=a.x*wv; acc[1]+=a.y*wv; acc[2]+=a.z*wv; acc[3]+=a.w*wv;
      acc[4]+=b.x*wv; acc[5]+=b.y*wv; acc[6]+=b.z*wv; acc[7]+=b.w*wv;
    }
    int h = j>>4, d = j&15;
    float* O = Os[mmat];
#pragma unroll
    for (int r=0;r<R;++r){
      int row = row0+r; int bidx = row>>9, n = row&(NN-1);
      O[(((size_t)bidx*HHC + h)*NN + n)*DHC + d] = acc[r];
    }
  }
}

// ---------- adjacency (+self loop) bitmask ----------
__global__ __launch_bounds__(256) void k_mask(const int* __restrict__ adj,
                                              unsigned long long* __restrict__ mb)
{
  size_t idx = (size_t)blockIdx.x*256 + threadIdx.x;
  int m = (int)(idx & (NN-1));
  int n = (int)((idx >> 9) & (NN-1));
  int val = (adj[idx] != 0) || (m==n);
  unsigned long long bal = __ballot(val);
  if ((threadIdx.x & 63) == 0) mb[idx>>6] = bal;
}

// ---------- edge-bias MLP: one thread per (b,n,m); out bf16 [B,H,N,N] ----------
__global__ __launch_bounds__(256) void k_edge(
  const float* __restrict__ ea,
  const float* __restrict__ eg, const float* __restrict__ ebi,
  const float* __restrict__ We1, const float* __restrict__ be1,
  const float* __restrict__ We2, const float* __restrict__ be2,
  bf16* __restrict__ ebias)
{
  __shared__ float W1[EEC*32], W2[32*HHC], B1[32], B2[HHC], G[EEC], Bv[EEC];
  int tid = threadIdx.x;
  for (int i=tid;i<EEC*32;i+=256) W1[i]=We1[i];
  if (tid<32*HHC) W2[tid]=We2[tid];
  if (tid<32)  B1[tid]=be1[tid];
  if (tid<HHC) B2[tid]=be2[tid];
  if (tid<EEC){ G[tid]=eg[tid]; Bv[tid]=ebi[tid]; }
  __syncthreads();
  size_t idx = (size_t)blockIdx.x*256 + tid;
  const float4* p = (const float4*)(ea + idx*EEC);
  float4 a0=p[0], a1=p[1], a2=p[2], a3=p[3];
  float e[EEC] = {a0.x,a0.y,a0.z,a0.w, a1.x,a1.y,a1.z,a1.w,
                  a2.x,a2.y,a2.z,a2.w, a3.x,a3.y,a3.z,a3.w};
  float s=0.f, q=0.f;
#pragma unroll
  for (int i=0;i<EEC;++i){ s+=e[i]; q+=e[i]*e[i]; }
  float mean = s*(1.f/EEC);
  float var  = q*(1.f/EEC) - mean*mean;
  float rstd = rsqrtf(var+1e-5f);
#pragma unroll
  for (int i=0;i<EEC;++i) e[i] = (e[i]-mean)*rstd*G[i] + Bv[i];
  float hid[32];
#pragma unroll
  for (int jj=0;jj<32;++jj) hid[jj]=B1[jj];
#pragma unroll
  for (int i=0;i<EEC;++i){
    float ei = e[i];
    const float4* w4 = (const float4*)&W1[i*32];
#pragma unroll
    for (int j4=0;j4<8;++j4){
      float4 wv = w4[j4];
      hid[j4*4+0]+=ei*wv.x; hid[j4*4+1]+=ei*wv.y;
      hid[j4*4+2]+=ei*wv.z; hid[j4*4+3]+=ei*wv.w;
    }
  }
#pragma unroll
  for (int jj=0;jj<32;++jj) hid[jj]=fmaxf(hid[jj],0.f);
  float o8[8];
#pragma unroll
  for (int hh=0;hh<HHC;++hh) o8[hh]=B2[hh];
#pragma unroll
  for (int jj=0;jj<32;++jj){
    float hj = hid[jj];
    const float4* w4 = (const float4*)&W2[jj*HHC];
    float4 wa=w4[0], wb=w4[1];
    o8[0]+=hj*wa.x; o8[1]+=hj*wa.y; o8[2]+=hj*wa.z; o8[3]+=hj*wa.w;
    o8[4]+=hj*wb.x; o8[5]+=hj*wb.y; o8[6]+=hj*wb.z; o8[7]+=hj*wb.w;
  }
  int b  = (int)(idx >> 18);             // N*N = 2^18
  int nm = (int)(idx & ((size_t)NN*NN-1));
  bf16* dst = ebias + ((size_t)b*HHC)*NN*NN + nm;
#pragma unroll
  for (int hh=0;hh<HHC;++hh){
    float y  = fminf(fmaxf(2.f*o8[hh], -30.f), 30.f);
    float ex = __expf(y);
    float t  = (ex-1.f)/(ex+1.f);        // tanh
    dst[(size_t)hh*NN*NN] = __float2bfloat16(5.f*t);
  }
}

// ---------- attention: block = (b,h,16-row tile); K,V transposed in LDS ----------
__global__ __launch_bounds__(256) void k_attn(
  const float* __restrict__ Qb, const float* __restrict__ Kb, const float* __restrict__ Vb,
  const bf16* __restrict__ ebias, const unsigned long long* __restrict__ mbits,
  float* __restrict__ ctxb)
{
  const int AR = 16;
  __shared__ float Kt[DHC][NN];          // 32KB
  __shared__ float Vt[DHC][NN];          // 32KB  (total exactly 64KB)
  int tid=threadIdx.x, w=tid>>6, lane=tid&63;
  int bh   = blockIdx.x / (NN/AR);
  int tile = blockIdx.x % (NN/AR);
  int b = bh>>3, h = bh&7; (void)h;
  const float* Ks = Kb + (size_t)bh*NN*DHC;
  const float* Vs = Vb + (size_t)bh*NN*DHC;
  for (int i=tid;i<NN*DHC;i+=256){
    int m=i>>4, d=i&15;
    Kt[d][m]=Ks[i];
    Vt[d][m]=Vs[i];
  }
  __syncthreads();
#pragma unroll
  for (int rr=0;rr<AR/4;++rr){
    int n = tile*AR + w*(AR/4) + rr;     // wave-uniform row
    const float* qp = Qb + ((size_t)bh*NN + n)*DHC;
    float qv[DHC];
#pragma unroll
    for (int d=0;d<DHC;++d) qv[d]=qp[d];
    const bf16* er = ebias + ((size_t)bh*NN + n)*NN;
    const unsigned long long* mrow = mbits + (size_t)(b*NN + n)*(NN/64);
    float sreg[8];
    float mx = -3.0e38f;
#pragma unroll
    for (int t=0;t<8;++t){
      int m = t*64+lane;
      float s = 0.f;
#pragma unroll
      for (int d=0;d<DHC;++d) s += qv[d]*Kt[d][m];
      s *= 0.25f;                        // / SCALE
      s += __bfloat162float(er[m]);      // tanh(eb)*5 already applied
      s = (s>=0.f) ? s : 0.2f*s;         // LeakyReLU
      unsigned long long wm = mrow[t];
      if (!((wm>>lane)&1ull)) s = -3.0e38f;
      sreg[t]=s;
      mx = fmaxf(mx,s);
    }
    mx = wmax(mx);
    float ps = 0.f;
#pragma unroll
    for (int t=0;t<8;++t){ float p = __expf(sreg[t]-mx); sreg[t]=p; ps+=p; }
    ps = wsum(ps);
    float inv = 1.f/ps;
    float acc[DHC];
#pragma unroll
    for (int d=0;d<DHC;++d) acc[d]=0.f;
#pragma unroll
    for (int t=0;t<8;++t){
      int m=t*64+lane;
      float p = sreg[t];
#pragma unroll
      for (int d=0;d<DHC;++d) acc[d] += p*Vt[d][m];
    }
#pragma unroll
    for (int d=0;d<DHC;++d) acc[d]=wsum(acc[d]);
    float vout = 0.f;
#pragma unroll
    for (int d=0;d<DHC;++d) vout = (lane==d)? acc[d]*inv : vout;   // no dyn reg index
    if (lane<DHC) ctxb[(size_t)(b*NN+n)*DOUTC + (bh&7)*DHC + lane] = vout;
  }
}

// ---------- h = xp+ctx; LN2; FFN; out = h + ffn : 16 rows per block ----------
__global__ __launch_bounds__(256) void k_ffn(
  const float* __restrict__ xp, const float* __restrict__ ctxb,
  const float* __restrict__ g2, const float* __restrict__ b2v,
  const float* __restrict__ W1, const float* __restrict__ bb1,
  const float* __restrict__ W2, const float* __restrict__ bb2,
  float* __restrict__ out)
{
  const int R = 16, P = 20;              // P=20 pad: 80B rows, float4-aligned
  __shared__ float hrow[R][DOUTC];       // 8KB
  __shared__ float hn[DOUTC*P];          // 10.2KB (transposed)
  __shared__ float hid[256*P];           // 20.5KB (transposed)
  int tid=threadIdx.x, w=tid>>6, lane=tid&63;
  int row0 = blockIdx.x*R;
  for (int i=tid;i<R*DOUTC;i+=256){
    int r=i>>7, c=i&127;
    size_t gi = (size_t)(row0+r)*DOUTC + c;
    hrow[r][c] = xp[gi] + ctxb[gi];
  }
  __syncthreads();
  float ga=g2[lane], gb=g2[lane+64], ba=b2v[lane], bbx=b2v[lane+64];
  for (int r=w; r<R; r+=4){
    float a = hrow[r][lane], c = hrow[r][lane+64];
    float s = wsum(a+c);
    float q = wsum(a*a+c*c);
    float mean = s*(1.f/DOUTC);
    float var  = q*(1.f/DOUTC)-mean*mean;
    float rstd = rsqrtf(var+1e-5f);
    hn[lane*P + r]      = (a-mean)*rstd*ga + ba;
    hn[(lane+64)*P + r] = (c-mean)*rstd*gb + bbx;
  }
  __syncthreads();
  { // hidden col j = tid
    int j=tid;
    float acc[R];
    float bj = bb1[j];
#pragma unroll
    for (int r=0;r<R;++r) acc[r]=bj;
    for (int i=0;i<DOUTC;++i){
      float wv = W1[i*256 + j];
      const float4* xa = (const float4*)&hn[i*P];
      float4 a=xa[0], b=xa[1], c=xa[2], d=xa[3];
      acc[0]+=a.x*wv;  acc[1]+=a.y*wv;  acc[2]+=a.z*wv;  acc[3]+=a.w*wv;
      acc[4]+=b.x*wv;  acc[5]+=b.y*wv;  acc[6]+=b.z*wv;  acc[7]+=b.w*wv;
      acc[8]+=c.x*wv;  acc[9]+=c.y*wv;  acc[10]+=c.z*wv; acc[11]+=c.w*wv;
      acc[12]+=d.x*wv; acc[13]+=d.y*wv; acc[14]+=d.z*wv; acc[15]+=d.w*wv;
    }
#pragma unroll
    for (int r=0;r<R;++r) hid[j*P+r] = fmaxf(acc[r],0.f);
  }
  __syncthreads();
  { // out col j2, 8 rows per thread
    int j2 = tid&127, r0 = (tid>>7)*8;
    float acc[8];
#pragma unroll
    for (int r=0;r<8;++r) acc[r]=0.f;
    for (int i=0;i<256;++i){
      float wv = W2[i*DOUTC + j2];
      const float4* xa = (const float4*)&hid[i*P + r0];
      float4 a=xa[0], b=xa[1];
      acc[0]+=a.x*wv; acc[1]+=a.y*wv; acc[2]+=a.z*wv; acc[3]+=a.w*wv;
      acc[4]+=b.x*wv; acc[5]+=b.y*wv; acc[6]+=b.z*wv; acc[7]+=b.w*wv;
    }
    float bj = bb2[j2];
#pragma unroll
    for (int r=0;r<8;++r)
      out[(size_t)(row0+r0+r)*DOUTC + j2] = hrow[r0+r][j2] + acc[r] + bj;
  }
}

extern "C" void kernel_launch(void* const* d_in, const int* in_sizes, int n_in,
                              void* d_out, int out_size, void* d_ws, size_t ws_size,
                              hipStream_t stream)
{
  const float* x     = (const float*)d_in[0];
  const int*   adj   = (const int*)  d_in[1];
  const float* ea    = (const float*)d_in[2];
  const float* ln1_g = (const float*)d_in[3];
  const float* ln1_b = (const float*)d_in[4];
  const float* Wp    = (const float*)d_in[5];
  const float* bp    = (const float*)d_in[6];
  const float* eln_g = (const float*)d_in[7];
  const float* eln_b = (const float*)d_in[8];
  const float* We1   = (const float*)d_in[9];
  const float* be1   = (const float*)d_in[10];
  const float* We2   = (const float*)d_in[11];
  const float* be2   = (const float*)d_in[12];
  const float* Wq    = (const float*)d_in[13];
  const float* Wk    = (const float*)d_in[14];
  const float* Wv    = (const float*)d_in[15];
  const float* ffW1  = (const float*)d_in[16];
  const float* ffb1  = (const float*)d_in[17];
  const float* ffW2  = (const float*)d_in[18];
  const float* ffb2  = (const float*)d_in[19];
  const float* ln2_g = (const float*)d_in[20];
  const float* ln2_b = (const float*)d_in[21];
  float* out = (float*)d_out;

  char* ws = (char*)d_ws;
  float* xp  = (float*)(ws);                         // 2MB
  float* Qb  = (float*)(ws + ((size_t)2<<20));       // 2MB
  float* Kb  = (float*)(ws + ((size_t)4<<20));       // 2MB
  float* Vb  = (float*)(ws + ((size_t)6<<20));       // 2MB
  float* ctx = (float*)(ws + ((size_t)8<<20));       // 2MB
  bf16*  eb  = (bf16*) (ws + ((size_t)10<<20));      // 32MB  [B,H,N,N]
  unsigned long long* mb = (unsigned long long*)(ws + ((size_t)42<<20)); // 256KB

  k_proj<<<(BB*NN)/8, 128, 0, stream>>>(x, ln1_g, ln1_b, Wp, bp, Wq, Wk, Wv, xp, Qb, Kb, Vb);
  k_mask<<<(BB*NN*NN)/256, 256, 0, stream>>>(adj, mb);
  k_edge<<<(BB*NN*NN)/256, 256, 0, stream>>>(ea, eln_g, eln_b, We1, be1, We2, be2, eb);
  k_attn<<<BB*HHC*(NN/16), 256, 0, stream>>>(Qb, Kb, Vb, eb, mb, ctx);
  k_ffn<<<(BB*NN)/16, 256, 0, stream>>>(xp, ctx, ln2_g, ln2_b, ffW1, ffb1, ffW2, ffb2, out);
}

// Round 2
// 135.021 us; speedup vs baseline: 1.6614x; 1.6614x over previous
//
#include <hip/hip_runtime.h>
#include <hip/hip_bf16.h>

#define BB 8
#define NN 512
#define DINC 128
#define DOUTC 128
#define HHC 8
#define EEC 16
#define DHC 16

typedef _Float16 h4 __attribute__((ext_vector_type(4)));
typedef float f32x4 __attribute__((ext_vector_type(4)));

__device__ __forceinline__ float wsum(float v){
#pragma unroll
  for (int o=1;o<64;o<<=1) v += __shfl_xor(v,o);
  return v;
}

// ---------- LN1 + Wp + Q/K/V projections: 8 rows per 128-thread block ----------
__global__ __launch_bounds__(128) void k_proj(
    const float* __restrict__ x,
    const float* __restrict__ g1, const float* __restrict__ b1,
    const float* __restrict__ Wp, const float* __restrict__ bp,
    const float* __restrict__ Wq, const float* __restrict__ Wk, const float* __restrict__ Wv,
    float* __restrict__ xp, _Float16* __restrict__ Qh, _Float16* __restrict__ Kh, _Float16* __restrict__ Vh)
{
  const int R = 8, P = 12;                 // P=12 pad: 48B rows, float4-aligned
  __shared__ float xln[DINC*P];
  __shared__ float xps[DINC*P];
  __shared__ float part[2][R][2];
  int tid = threadIdx.x, w = tid>>6, lane = tid&63;
  int row0 = blockIdx.x * R;
  float v[R];
#pragma unroll
  for (int r=0;r<R;++r) v[r] = x[(size_t)(row0+r)*DINC + tid];
  float gg = g1[tid], bbv = b1[tid];
#pragma unroll
  for (int r=0;r<R;++r){
    float s = wsum(v[r]);
    float q = wsum(v[r]*v[r]);
    if (lane==0){ part[w][r][0]=s; part[w][r][1]=q; }
  }
  __syncthreads();
#pragma unroll
  for (int r=0;r<R;++r){
    float s = part[0][r][0]+part[1][r][0];
    float q = part[0][r][1]+part[1][r][1];
    float mean = s*(1.f/DINC);
    float var  = q*(1.f/DINC) - mean*mean;
    float rstd = rsqrtf(var + 1e-5f);
    xln[tid*P + r] = (v[r]-mean)*rstd*gg + bbv;
  }
  __syncthreads();
  int j = tid;
  float acc[R];
  { // xp = xln @ Wp + bp
    float bj = bp[j];
#pragma unroll
    for (int r=0;r<R;++r) acc[r]=bj;
    for (int i=0;i<DINC;++i){
      float wv = Wp[i*DOUTC + j];
      const float4* xa = (const float4*)&xln[i*P];
      float4 a = xa[0], b = xa[1];
      acc[0]+=a.x*wv; acc[1]+=a.y*wv; acc[2]+=a.z*wv; acc[3]+=a.w*wv;
      acc[4]+=b.x*wv; acc[5]+=b.y*wv; acc[6]+=b.z*wv; acc[7]+=b.w*wv;
    }
#pragma unroll
    for (int r=0;r<R;++r){
      xps[j*P + r] = acc[r];
      xp[(size_t)(row0+r)*DOUTC + j] = acc[r];
    }
  }
  __syncthreads();
  const float* Ws[3] = {Wq, Wk, Wv};
  _Float16* Os[3] = {Qh, Kh, Vh};
#pragma unroll
  for (int mmat=0;mmat<3;++mmat){
    const float* W = Ws[mmat];
#pragma unroll
    for (int r=0;r<R;++r) acc[r]=0.f;
    for (int i=0;i<DINC;++i){
      float wv = W[i*DOUTC + j];
      const float4* xa = (const float4*)&xps[i*P];
      float4 a = xa[0], b = xa[1];
      acc[0]+=a.x*wv; acc[1]+=a.y*wv; acc[2]+=a.z*wv; acc[3]+=a.w*wv;
      acc[4]+=b.x*wv; acc[5]+=b.y*wv; acc[6]+=b.z*wv; acc[7]+=b.w*wv;
    }
    int h = j>>4, d = j&15;
    _Float16* O = Os[mmat];
#pragma unroll
    for (int r=0;r<R;++r){
      int row = row0+r; int bidx = row>>9, n = row&(NN-1);
      O[(((size_t)bidx*HHC + h)*NN + n)*DHC + d] = (_Float16)acc[r];
    }
  }
}

// ---------- edge-bias MLP + adjacency mask fused: one thread per (b,n,m) ----------
// output f16 [B,H,N,N]; masked entries = -30000 (exp underflows to exactly 0)
__global__ __launch_bounds__(256) void k_edge(
  const float* __restrict__ ea, const int* __restrict__ adj,
  const float* __restrict__ eg, const float* __restrict__ ebi,
  const float* __restrict__ We1, const float* __restrict__ be1,
  const float* __restrict__ We2, const float* __restrict__ be2,
  _Float16* __restrict__ ebias)
{
  __shared__ float W1[EEC*32], W2[32*HHC], B1[32], B2[HHC], G[EEC], Bv[EEC];
  int tid = threadIdx.x;
  for (int i=tid;i<EEC*32;i+=256) W1[i]=We1[i];
  if (tid<32*HHC) W2[tid]=We2[tid];
  if (tid<32)  B1[tid]=be1[tid];
  if (tid<HHC) B2[tid]=be2[tid];
  if (tid<EEC){ G[tid]=eg[tid]; Bv[tid]=ebi[tid]; }
  __syncthreads();
  size_t idx = (size_t)blockIdx.x*256 + tid;
  int m = (int)(idx & (NN-1));
  int n = (int)((idx >> 9) & (NN-1));
  int ok = (adj[idx] != 0) || (n == m);
  const float4* p = (const float4*)(ea + idx*EEC);
  float4 a0=p[0], a1=p[1], a2=p[2], a3=p[3];
  float e[EEC] = {a0.x,a0.y,a0.z,a0.w, a1.x,a1.y,a1.z,a1.w,
                  a2.x,a2.y,a2.z,a2.w, a3.x,a3.y,a3.z,a3.w};
  float s=0.f, q=0.f;
#pragma unroll
  for (int i=0;i<EEC;++i){ s+=e[i]; q+=e[i]*e[i]; }
  float mean = s*(1.f/EEC);
  float var  = q*(1.f/EEC) - mean*mean;
  float rstd = rsqrtf(var+1e-5f);
#pragma unroll
  for (int i=0;i<EEC;++i) e[i] = (e[i]-mean)*rstd*G[i] + Bv[i];
  float hid[32];
#pragma unroll
  for (int jj=0;jj<32;++jj) hid[jj]=B1[jj];
#pragma unroll
  for (int i=0;i<EEC;++i){
    float ei = e[i];
    const float4* w4 = (const float4*)&W1[i*32];
#pragma unroll
    for (int j4=0;j4<8;++j4){
      float4 wv = w4[j4];
      hid[j4*4+0]+=ei*wv.x; hid[j4*4+1]+=ei*wv.y;
      hid[j4*4+2]+=ei*wv.z; hid[j4*4+3]+=ei*wv.w;
    }
  }
#pragma unroll
  for (int jj=0;jj<32;++jj) hid[jj]=fmaxf(hid[jj],0.f);
  float o8[8];
#pragma unroll
  for (int hh=0;hh<HHC;++hh) o8[hh]=B2[hh];
#pragma unroll
  for (int jj=0;jj<32;++jj){
    float hj = hid[jj];
    const float4* w4 = (const float4*)&W2[jj*HHC];
    float4 wa=w4[0], wb=w4[1];
    o8[0]+=hj*wa.x; o8[1]+=hj*wa.y; o8[2]+=hj*wa.z; o8[3]+=hj*wa.w;
    o8[4]+=hj*wb.x; o8[5]+=hj*wb.y; o8[6]+=hj*wb.z; o8[7]+=hj*wb.w;
  }
  int b  = (int)(idx >> 18);             // N*N = 2^18
  int nm = (int)(idx & ((size_t)NN*NN-1));
  _Float16* dst = ebias + ((size_t)b*HHC)*NN*NN + nm;
#pragma unroll
  for (int hh=0;hh<HHC;++hh){
    float y  = fminf(fmaxf(2.f*o8[hh], -30.f), 30.f);
    float ex = __expf(y);
    float t  = (ex-1.f)/(ex+1.f);        // tanh
    dst[(size_t)hh*NN*NN] = ok ? (_Float16)(5.f*t) : (_Float16)(-30000.f);
  }
}

// ---------- MFMA attention ----------
// block = (b,h, 64-row tile), 4 waves x 16 rows. S^T = mfma(K,Q) puts P directly
// in PV's A-fragment layout (T12 swapped-operand trick): softmax fully in-register.
__global__ __launch_bounds__(256) void k_attn(
  const _Float16* __restrict__ Qh, const _Float16* __restrict__ Kh, const _Float16* __restrict__ Vh,
  const _Float16* __restrict__ eb, float* __restrict__ ctxb)
{
  __shared__ _Float16 Klds[NN*DHC];      // 16KB, row-major [m][d]
  __shared__ _Float16 Vt[DHC*520];       // 16.25KB, transposed [d][m] (pad 520 kills bank conflicts)
  int tid = threadIdx.x;
  int bh   = blockIdx.x >> 3;
  int tile = blockIdx.x & 7;             // 8 tiles of 64 rows
  const _Float16* Kg = Kh + (size_t)bh*NN*DHC;
  const _Float16* Vg = Vh + (size_t)bh*NN*DHC;
  { // K: linear 16KB copy
    const float4* src = (const float4*)Kg;
    float4* dst = (float4*)Klds;
#pragma unroll
    for (int i=tid;i<1024;i+=256) dst[i]=src[i];
  }
  { // V: transpose-stage
#pragma unroll
    for (int i=tid;i<1024;i+=256){
      int m = i>>1, hf = i&1;
      float4 v4 = *(const float4*)(Vg + (size_t)m*DHC + hf*8);
      const _Float16* hh = (const _Float16*)&v4;
#pragma unroll
      for (int jj=0;jj<8;++jj) Vt[(hf*8+jj)*520 + m] = hh[jj];
    }
  }
  __syncthreads();

  int w = tid>>6, lane = tid&63;
  int c = lane&15, g = lane>>4;
  int n0 = tile*64 + w*16;

  // Q B-fragment: lane holds Q[n0+c][4g..4g+3]
  h4 qf = *(const h4*)(Qh + ((size_t)bh*NN + n0 + c)*DHC + 4*g);
  const _Float16* ebw = eb + ((size_t)bh*NN + n0 + c)*NN + 4*g;

  float s[32][4];
  float mx = -3.0e38f;
  f32x4 zero = {0.f,0.f,0.f,0.f};
#pragma unroll
  for (int t=0;t<32;++t){
    // A = K fragment: K[16t+c][4g..4g+3]  ->  D = S^T tile: lane holds (m=16t+4g+r, n=c)
    h4 kf = *(const h4*)(Klds + (16*t + c)*DHC + 4*g);
    f32x4 d = __builtin_amdgcn_mfma_f32_16x16x16f16(kf, qf, zero, 0, 0, 0);
    h4 e4 = *(const h4*)(ebw + 16*t);    // eb[n0+c][16t+4g+r], mask pre-merged
#pragma unroll
    for (int r=0;r<4;++r){
      float sv = d[r]*0.25f + (float)e4[r];
      sv = fmaxf(sv,0.f) + 0.2f*fminf(sv,0.f);   // LeakyReLU(0.2)
      s[t][r] = sv;
      mx = fmaxf(mx, sv);
    }
  }
  // row max: lane's values all belong to row n=c; combine across g-groups
  mx = fmaxf(mx, __shfl_xor(mx,16));
  mx = fmaxf(mx, __shfl_xor(mx,32));

  float rowsum = 0.f;
  f32x4 acc = zero;
#pragma unroll
  for (int t=0;t<32;++t){
    float p0=__expf(s[t][0]-mx), p1=__expf(s[t][1]-mx);
    float p2=__expf(s[t][2]-mx), p3=__expf(s[t][3]-mx);
    rowsum += (p0+p1)+(p2+p3);
    h4 pa; pa[0]=(_Float16)p0; pa[1]=(_Float16)p1; pa[2]=(_Float16)p2; pa[3]=(_Float16)p3;
    // B = V fragment: V[16t+4g+j][d=c] = Vt[c][16t+4g+j]
    h4 vf = *(const h4*)(Vt + c*520 + 16*t + 4*g);
    acc = __builtin_amdgcn_mfma_f32_16x16x16f16(pa, vf, acc, 0, 0, 0);
  }
  rowsum += __shfl_xor(rowsum,16);
  rowsum += __shfl_xor(rowsum,32);

  int b = bh>>3, h = bh&7;
#pragma unroll
  for (int r=0;r<4;++r){
    // ctx D-layout: lane holds (n = n0+4g+r, d = c); fetch row (4g+r)'s sum from lane 20g+r
    float sr = __shfl(rowsum, g*16 + 4*g + r);
    ctxb[((size_t)b*NN + n0 + 4*g + r)*DOUTC + h*DHC + c] = acc[r]/sr;
  }
}

// ---------- h = xp+ctx; LN2; FFN; out = h + ffn : 16 rows per block ----------
__global__ __launch_bounds__(256) void k_ffn(
  const float* __restrict__ xp, const float* __restrict__ ctxb,
  const float* __restrict__ g2, const float* __restrict__ b2v,
  const float* __restrict__ W1, const float* __restrict__ bb1,
  const float* __restrict__ W2, const float* __restrict__ bb2,
  float* __restrict__ out)
{
  const int R = 16, P = 20;              // P=20 pad: 80B rows, float4-aligned
  __shared__ float hrow[R][DOUTC];       // 8KB
  __shared__ float hn[DOUTC*P];          // 10.2KB (transposed)
  __shared__ float hid[256*P];           // 20.5KB (transposed)
  int tid=threadIdx.x, w=tid>>6, lane=tid&63;
  int row0 = blockIdx.x*R;
  for (int i=tid;i<R*DOUTC;i+=256){
    int r=i>>7, c=i&127;
    size_t gi = (size_t)(row0+r)*DOUTC + c;
    hrow[r][c] = xp[gi] + ctxb[gi];
  }
  __syncthreads();
  float ga=g2[lane], gb=g2[lane+64], ba=b2v[lane], bbx=b2v[lane+64];
  for (int r=w; r<R; r+=4){
    float a = hrow[r][lane], c = hrow[r][lane+64];
    float s = wsum(a+c);
    float q = wsum(a*a+c*c);
    float mean = s*(1.f/DOUTC);
    float var  = q*(1.f/DOUTC)-mean*mean;
    float rstd = rsqrtf(var+1e-5f);
    hn[lane*P + r]      = (a-mean)*rstd*ga + ba;
    hn[(lane+64)*P + r] = (c-mean)*rstd*gb + bbx;
  }
  __syncthreads();
  { // hidden col j = tid
    int j=tid;
    float acc[R];
    float bj = bb1[j];
#pragma unroll
    for (int r=0;r<R;++r) acc[r]=bj;
    for (int i=0;i<DOUTC;++i){
      float wv = W1[i*256 + j];
      const float4* xa = (const float4*)&hn[i*P];
      float4 a=xa[0], b=xa[1], c=xa[2], d=xa[3];
      acc[0]+=a.x*wv;  acc[1]+=a.y*wv;  acc[2]+=a.z*wv;  acc[3]+=a.w*wv;
      acc[4]+=b.x*wv;  acc[5]+=b.y*wv;  acc[6]+=b.z*wv;  acc[7]+=b.w*wv;
      acc[8]+=c.x*wv;  acc[9]+=c.y*wv;  acc[10]+=c.z*wv; acc[11]+=c.w*wv;
      acc[12]+=d.x*wv; acc[13]+=d.y*wv; acc[14]+=d.z*wv; acc[15]+=d.w*wv;
    }
#pragma unroll
    for (int r=0;r<R;++r) hid[j*P+r] = fmaxf(acc[r],0.f);
  }
  __syncthreads();
  { // out col j2, 8 rows per thread
    int j2 = tid&127, r0 = (tid>>7)*8;
    float acc[8];
#pragma unroll
    for (int r=0;r<8;++r) acc[r]=0.f;
    for (int i=0;i<256;++i){
      float wv = W2[i*DOUTC + j2];
      const float4* xa = (const float4*)&hid[i*P + r0];
      float4 a=xa[0], b=xa[1];
      acc[0]+=a.x*wv; acc[1]+=a.y*wv; acc[2]+=a.z*wv; acc[3]+=a.w*wv;
      acc[4]+=b.x*wv; acc[5]+=b.y*wv; acc[6]+=b.z*wv; acc[7]+=b.w*wv;
    }
    float bj = bb2[j2];
#pragma unroll
    for (int r=0;r<8;++r)
      out[(size_t)(row0+r0+r)*DOUTC + j2] = hrow[r0+r][j2] + acc[r] + bj;
  }
}

extern "C" void kernel_launch(void* const* d_in, const int* in_sizes, int n_in,
                              void* d_out, int out_size, void* d_ws, size_t ws_size,
                              hipStream_t stream)
{
  const float* x     = (const float*)d_in[0];
  const int*   adj   = (const int*)  d_in[1];
  const float* ea    = (const float*)d_in[2];
  const float* ln1_g = (const float*)d_in[3];
  const float* ln1_b = (const float*)d_in[4];
  const float* Wp    = (const float*)d_in[5];
  const float* bp    = (const float*)d_in[6];
  const float* eln_g = (const float*)d_in[7];
  const float* eln_b = (const float*)d_in[8];
  const float* We1   = (const float*)d_in[9];
  const float* be1   = (const float*)d_in[10];
  const float* We2   = (const float*)d_in[11];
  const float* be2   = (const float*)d_in[12];
  const float* Wq    = (const float*)d_in[13];
  const float* Wk    = (const float*)d_in[14];
  const float* Wv    = (const float*)d_in[15];
  const float* ffW1  = (const float*)d_in[16];
  const float* ffb1  = (const float*)d_in[17];
  const float* ffW2  = (const float*)d_in[18];
  const float* ffb2  = (const float*)d_in[19];
  const float* ln2_g = (const float*)d_in[20];
  const float* ln2_b = (const float*)d_in[21];
  float* out = (float*)d_out;

  char* ws = (char*)d_ws;
  float*    xp  = (float*)(ws);                       // 2MB
  float*    ctx = (float*)(ws + ((size_t)2<<20));     // 2MB
  _Float16* Qh  = (_Float16*)(ws + ((size_t)4<<20));  // 1MB
  _Float16* Kh  = (_Float16*)(ws + ((size_t)5<<20));  // 1MB
  _Float16* Vh  = (_Float16*)(ws + ((size_t)6<<20));  // 1MB
  _Float16* ebf = (_Float16*)(ws + ((size_t)7<<20));  // 32MB [B,H,N,N] f16 (mask merged)

  k_proj<<<(BB*NN)/8, 128, 0, stream>>>(x, ln1_g, ln1_b, Wp, bp, Wq, Wk, Wv, xp, Qh, Kh, Vh);
  k_edge<<<(BB*NN*NN)/256, 256, 0, stream>>>(ea, adj, eln_g, eln_b, We1, be1, We2, be2, ebf);
  k_attn<<<BB*HHC*8, 256, 0, stream>>>(Qh, Kh, Vh, ebf, ctx);
  k_ffn<<<(BB*NN)/16, 256, 0, stream>>>(xp, ctx, ln2_g, ln2_b, ffW1, ffb1, ffW2, ffb2, out);
}

// Round 3
// 116.054 us; speedup vs baseline: 1.9329x; 1.1634x over previous
//
#include <hip/hip_runtime.h>
#include <hip/hip_bf16.h>

#define BB 8
#define NN 512
#define DINC 128
#define DOUTC 128
#define HHC 8
#define EEC 16
#define DHC 16

typedef _Float16 h4 __attribute__((ext_vector_type(4)));
typedef float f32x4 __attribute__((ext_vector_type(4)));

__device__ __forceinline__ float wsum(float v){
#pragma unroll
  for (int o=1;o<64;o<<=1) v += __shfl_xor(v,o);
  return v;
}

// ---------- LN1 + Wp + Q/K/V projections: 8 rows per 128-thread block ----------
__global__ __launch_bounds__(128) void k_proj(
    const float* __restrict__ x,
    const float* __restrict__ g1, const float* __restrict__ b1,
    const float* __restrict__ Wp, const float* __restrict__ bp,
    const float* __restrict__ Wq, const float* __restrict__ Wk, const float* __restrict__ Wv,
    float* __restrict__ xp, _Float16* __restrict__ Qh, _Float16* __restrict__ Kh, _Float16* __restrict__ Vh)
{
  const int R = 8, P = 12;                 // P=12 pad: 48B rows, float4-aligned
  __shared__ float xln[DINC*P];
  __shared__ float xps[DINC*P];
  __shared__ float part[2][R][2];
  int tid = threadIdx.x, w = tid>>6, lane = tid&63;
  int row0 = blockIdx.x * R;
  float v[R];
#pragma unroll
  for (int r=0;r<R;++r) v[r] = x[(size_t)(row0+r)*DINC + tid];
  float gg = g1[tid], bbv = b1[tid];
#pragma unroll
  for (int r=0;r<R;++r){
    float s = wsum(v[r]);
    float q = wsum(v[r]*v[r]);
    if (lane==0){ part[w][r][0]=s; part[w][r][1]=q; }
  }
  __syncthreads();
#pragma unroll
  for (int r=0;r<R;++r){
    float s = part[0][r][0]+part[1][r][0];
    float q = part[0][r][1]+part[1][r][1];
    float mean = s*(1.f/DINC);
    float var  = q*(1.f/DINC) - mean*mean;
    float rstd = rsqrtf(var + 1e-5f);
    xln[tid*P + r] = (v[r]-mean)*rstd*gg + bbv;
  }
  __syncthreads();
  int j = tid;
  float acc[R];
  { // xp = xln @ Wp + bp
    float bj = bp[j];
#pragma unroll
    for (int r=0;r<R;++r) acc[r]=bj;
    for (int i=0;i<DINC;++i){
      float wv = Wp[i*DOUTC + j];
      const float4* xa = (const float4*)&xln[i*P];
      float4 a = xa[0], b = xa[1];
      acc[0]+=a.x*wv; acc[1]+=a.y*wv; acc[2]+=a.z*wv; acc[3]+=a.w*wv;
      acc[4]+=b.x*wv; acc[5]+=b.y*wv; acc[6]+=b.z*wv; acc[7]+=b.w*wv;
    }
#pragma unroll
    for (int r=0;r<R;++r){
      xps[j*P + r] = acc[r];
      xp[(size_t)(row0+r)*DOUTC + j] = acc[r];
    }
  }
  __syncthreads();
  const float* Ws[3] = {Wq, Wk, Wv};
  _Float16* Os[3] = {Qh, Kh, Vh};
#pragma unroll
  for (int mmat=0;mmat<3;++mmat){
    const float* W = Ws[mmat];
#pragma unroll
    for (int r=0;r<R;++r) acc[r]=0.f;
    for (int i=0;i<DINC;++i){
      float wv = W[i*DOUTC + j];
      const float4* xa = (const float4*)&xps[i*P];
      float4 a = xa[0], b = xa[1];
      acc[0]+=a.x*wv; acc[1]+=a.y*wv; acc[2]+=a.z*wv; acc[3]+=a.w*wv;
      acc[4]+=b.x*wv; acc[5]+=b.y*wv; acc[6]+=b.z*wv; acc[7]+=b.w*wv;
    }
    int h = j>>4, d = j&15;
    _Float16* O = Os[mmat];
#pragma unroll
    for (int r=0;r<R;++r){
      int row = row0+r; int bidx = row>>9, n = row&(NN-1);
      O[(((size_t)bidx*HHC + h)*NN + n)*DHC + d] = (_Float16)acc[r];
    }
  }
}

// ---------- edge-bias MLP via MFMA, mask fused: one block per (b,n) row ----------
// Both layers computed TRANSPOSED: D1 = W1^T x E^T gives Hid^T in exactly the
// B-fragment layout layer-2 needs (no cross-lane reshuffle).
// Output f16 [B,H,N,N]; masked entries = -30000 (exp underflows to exact 0).
__global__ __launch_bounds__(256) void k_edge(
  const float* __restrict__ ea, const int* __restrict__ adj,
  const float* __restrict__ eg, const float* __restrict__ ebi,
  const float* __restrict__ We1, const float* __restrict__ be1,
  const float* __restrict__ We2, const float* __restrict__ be2,
  _Float16* __restrict__ ebias)
{
  __shared__ _Float16 sm[8*520];          // out staging [h][m], pad 520 (bank-safe)
  __shared__ unsigned long long mrow[8];  // 512-bit adjacency mask for this row
  int tid = threadIdx.x, w = tid>>6, lane = tid&63;
  int c = lane&15, g = lane>>4;
  int bn = blockIdx.x;                    // b*512 + n
  int b = bn >> 9, n = bn & (NN-1);

  // adjacency bitmask (+ self loop)
#pragma unroll
  for (int i=tid;i<NN;i+=256){
    int val = (adj[(size_t)bn*NN + i] != 0) || (i==n);
    unsigned long long bal = __ballot(val);
    if (lane==0) mrow[i>>6] = bal;
  }

  // A-fragments of the (transposed) weights: lane holds A[c][4g+j]
  h4 w1a, w1b, w2a, w2b;
#pragma unroll
  for (int j=0;j<4;++j){
    w1a[j] = (_Float16)We1[(4*g+j)*32 + c];        // W1^T[c][4g+j], hid tile 0..15
    w1b[j] = (_Float16)We1[(4*g+j)*32 + 16 + c];   // hid tile 16..31
    w2a[j] = (_Float16)((c<8)? We2[(4*g+j)*HHC + c]      : 0.f);  // W2^T[c][4g+j]
    w2b[j] = (_Float16)((c<8)? We2[(16+4*g+j)*HHC + c]   : 0.f);
  }
  float4 b1a = *(const float4*)(be1 + 4*g);
  float4 b1b = *(const float4*)(be1 + 16 + 4*g);
  float4 b2r = *(const float4*)(be2 + (g&1)*4);    // be2[4g+r], valid for g<2
  float4 G4  = *(const float4*)(eg  + 4*g);
  float4 Bv4 = *(const float4*)(ebi + 4*g);
  __syncthreads();

  const float* eaRow = ea + (size_t)bn*NN*EEC;
#pragma unroll
  for (int k=0;k<8;++k){
    int m0 = (w*8 + k)*16;
    // E fragment: one coalesced dwordx4 per lane covers the 16x16 tile
    float4 v = *(const float4*)(eaRow + (size_t)(m0 + c)*EEC + 4*g);
    // LN over the 16 features (spread across the 4 g-groups of each edge c)
    float s = v.x+v.y+v.z+v.w;
    float q = v.x*v.x+v.y*v.y+v.z*v.z+v.w*v.w;
    s += __shfl_xor(s,16); s += __shfl_xor(s,32);
    q += __shfl_xor(q,16); q += __shfl_xor(q,32);
    float mean = s*(1.f/EEC);
    float var  = q*(1.f/EEC) - mean*mean;
    float rstd = rsqrtf(var + 1e-5f);
    h4 ef;
    ef[0]=(_Float16)((v.x-mean)*rstd*G4.x + Bv4.x);
    ef[1]=(_Float16)((v.y-mean)*rstd*G4.y + Bv4.y);
    ef[2]=(_Float16)((v.z-mean)*rstd*G4.z + Bv4.z);
    ef[3]=(_Float16)((v.w-mean)*rstd*G4.w + Bv4.w);
    // layer 1: Hid^T = W1^T x E^T + be1  (lane: Hid^T[4g+r][edge c])
    f32x4 d1a = {b1a.x,b1a.y,b1a.z,b1a.w};
    f32x4 d1b = {b1b.x,b1b.y,b1b.z,b1b.w};
    d1a = __builtin_amdgcn_mfma_f32_16x16x16f16(w1a, ef, d1a, 0, 0, 0);
    d1b = __builtin_amdgcn_mfma_f32_16x16x16f16(w1b, ef, d1b, 0, 0, 0);
    // relu; D-layout r-regs == B-fragment j-slots for layer 2
    h4 hfa, hfb;
#pragma unroll
    for (int r=0;r<4;++r){
      hfa[r] = (_Float16)fmaxf(d1a[r],0.f);
      hfb[r] = (_Float16)fmaxf(d1b[r],0.f);
    }
    // layer 2: out^T = W2^T x Hid^T  (lane g<2: out[edge c][h=4g+r])
    f32x4 d2 = {0.f,0.f,0.f,0.f};
    d2 = __builtin_amdgcn_mfma_f32_16x16x16f16(w2a, hfa, d2, 0, 0, 0);
    d2 = __builtin_amdgcn_mfma_f32_16x16x16f16(w2b, hfb, d2, 0, 0, 0);
    if (g < 2){
      int mm = m0 + c;
      bool ok = (mrow[mm>>6] >> (mm&63)) & 1ull;
#pragma unroll
      for (int r=0;r<4;++r){
        float y  = d2[r] + ((const float*)&b2r)[r];
        y = fminf(fmaxf(2.f*y,-30.f),30.f);
        float ex = __expf(y);
        float t  = (ex-1.f)/(ex+1.f);      // tanh
        sm[(4*g+r)*520 + mm] = ok ? (_Float16)(5.f*t) : (_Float16)(-30000.f);
      }
    }
  }
  __syncthreads();
  // cooperative write: 8 rows (one per head plane) x 1KB, coalesced
  size_t base = ((size_t)b*HHC)*NN*NN + (size_t)n*NN;
#pragma unroll
  for (int i=tid;i<512;i+=256){
    int h = i>>6, part = i&63;
    *(float4*)(ebias + base + (size_t)h*NN*NN + part*8) =
        *(const float4*)(sm + h*520 + part*8);
  }
}

// ---------- MFMA attention ----------
// block = (b,h, 64-row tile), 4 waves x 16 rows. S^T = mfma(K,Q) puts P directly
// in PV's A-fragment layout (T12 swapped-operand trick): softmax fully in-register.
__global__ __launch_bounds__(256) void k_attn(
  const _Float16* __restrict__ Qh, const _Float16* __restrict__ Kh, const _Float16* __restrict__ Vh,
  const _Float16* __restrict__ eb, float* __restrict__ ctxb)
{
  __shared__ _Float16 Klds[NN*DHC];      // 16KB, row-major [m][d]
  __shared__ _Float16 Vt[DHC*520];       // 16.25KB, transposed [d][m] (pad 520 kills bank conflicts)
  int tid = threadIdx.x;
  int bh   = blockIdx.x >> 3;
  int tile = blockIdx.x & 7;             // 8 tiles of 64 rows
  const _Float16* Kg = Kh + (size_t)bh*NN*DHC;
  const _Float16* Vg = Vh + (size_t)bh*NN*DHC;
  { // K: linear 16KB copy
    const float4* src = (const float4*)Kg;
    float4* dst = (float4*)Klds;
#pragma unroll
    for (int i=tid;i<1024;i+=256) dst[i]=src[i];
  }
  { // V: transpose-stage
#pragma unroll
    for (int i=tid;i<1024;i+=256){
      int m = i>>1, hf = i&1;
      float4 v4 = *(const float4*)(Vg + (size_t)m*DHC + hf*8);
      const _Float16* hh = (const _Float16*)&v4;
#pragma unroll
      for (int jj=0;jj<8;++jj) Vt[(hf*8+jj)*520 + m] = hh[jj];
    }
  }
  __syncthreads();

  int w = tid>>6, lane = tid&63;
  int c = lane&15, g = lane>>4;
  int n0 = tile*64 + w*16;

  // Q B-fragment: lane holds Q[n0+c][4g..4g+3]
  h4 qf = *(const h4*)(Qh + ((size_t)bh*NN + n0 + c)*DHC + 4*g);
  const _Float16* ebw = eb + ((size_t)bh*NN + n0 + c)*NN + 4*g;

  float s[32][4];
  float mx = -3.0e38f;
  f32x4 zero = {0.f,0.f,0.f,0.f};
#pragma unroll
  for (int t=0;t<32;++t){
    // A = K fragment: K[16t+c][4g..4g+3]  ->  D = S^T tile: lane holds (m=16t+4g+r, n=c)
    h4 kf = *(const h4*)(Klds + (16*t + c)*DHC + 4*g);
    f32x4 d = __builtin_amdgcn_mfma_f32_16x16x16f16(kf, qf, zero, 0, 0, 0);
    h4 e4 = *(const h4*)(ebw + 16*t);    // eb[n0+c][16t+4g+r], mask pre-merged
#pragma unroll
    for (int r=0;r<4;++r){
      float sv = d[r]*0.25f + (float)e4[r];
      sv = fmaxf(sv,0.f) + 0.2f*fminf(sv,0.f);   // LeakyReLU(0.2)
      s[t][r] = sv;
      mx = fmaxf(mx, sv);
    }
  }
  // row max: lane's values all belong to row n=c; combine across g-groups
  mx = fmaxf(mx, __shfl_xor(mx,16));
  mx = fmaxf(mx, __shfl_xor(mx,32));

  float rowsum = 0.f;
  f32x4 acc = zero;
#pragma unroll
  for (int t=0;t<32;++t){
    float p0=__expf(s[t][0]-mx), p1=__expf(s[t][1]-mx);
    float p2=__expf(s[t][2]-mx), p3=__expf(s[t][3]-mx);
    rowsum += (p0+p1)+(p2+p3);
    h4 pa; pa[0]=(_Float16)p0; pa[1]=(_Float16)p1; pa[2]=(_Float16)p2; pa[3]=(_Float16)p3;
    // B = V fragment: V[16t+4g+j][d=c] = Vt[c][16t+4g+j]
    h4 vf = *(const h4*)(Vt + c*520 + 16*t + 4*g);
    acc = __builtin_amdgcn_mfma_f32_16x16x16f16(pa, vf, acc, 0, 0, 0);
  }
  rowsum += __shfl_xor(rowsum,16);
  rowsum += __shfl_xor(rowsum,32);

  int b = bh>>3, h = bh&7;
#pragma unroll
  for (int r=0;r<4;++r){
    // ctx D-layout: lane holds (n = n0+4g+r, d = c); fetch row (4g+r)'s sum from lane 20g+r
    float sr = __shfl(rowsum, g*16 + 4*g + r);
    ctxb[((size_t)b*NN + n0 + 4*g + r)*DOUTC + h*DHC + c] = acc[r]/sr;
  }
}

// ---------- h = xp+ctx; LN2; FFN; out = h + ffn : 16 rows per block ----------
__global__ __launch_bounds__(256) void k_ffn(
  const float* __restrict__ xp, const float* __restrict__ ctxb,
  const float* __restrict__ g2, const float* __restrict__ b2v,
  const float* __restrict__ W1, const float* __restrict__ bb1,
  const float* __restrict__ W2, const float* __restrict__ bb2,
  float* __restrict__ out)
{
  const int R = 16, P = 20;              // P=20 pad: 80B rows, float4-aligned
  __shared__ float hrow[R][DOUTC];       // 8KB
  __shared__ float hn[DOUTC*P];          // 10.2KB (transposed)
  __shared__ float hid[256*P];           // 20.5KB (transposed)
  int tid=threadIdx.x, w=tid>>6, lane=tid&63;
  int row0 = blockIdx.x*R;
  for (int i=tid;i<R*DOUTC;i+=256){
    int r=i>>7, c=i&127;
    size_t gi = (size_t)(row0+r)*DOUTC + c;
    hrow[r][c] = xp[gi] + ctxb[gi];
  }
  __syncthreads();
  float ga=g2[lane], gb=g2[lane+64], ba=b2v[lane], bbx=b2v[lane+64];
  for (int r=w; r<R; r+=4){
    float a = hrow[r][lane], c = hrow[r][lane+64];
    float s = wsum(a+c);
    float q = wsum(a*a+c*c);
    float mean = s*(1.f/DOUTC);
    float var  = q*(1.f/DOUTC)-mean*mean;
    float rstd = rsqrtf(var+1e-5f);
    hn[lane*P + r]      = (a-mean)*rstd*ga + ba;
    hn[(lane+64)*P + r] = (c-mean)*rstd*gb + bbx;
  }
  __syncthreads();
  { // hidden col j = tid
    int j=tid;
    float acc[R];
    float bj = bb1[j];
#pragma unroll
    for (int r=0;r<R;++r) acc[r]=bj;
    for (int i=0;i<DOUTC;++i){
      float wv = W1[i*256 + j];
      const float4* xa = (const float4*)&hn[i*P];
      float4 a=xa[0], b=xa[1], c=xa[2], d=xa[3];
      acc[0]+=a.x*wv;  acc[1]+=a.y*wv;  acc[2]+=a.z*wv;  acc[3]+=a.w*wv;
      acc[4]+=b.x*wv;  acc[5]+=b.y*wv;  acc[6]+=b.z*wv;  acc[7]+=b.w*wv;
      acc[8]+=c.x*wv;  acc[9]+=c.y*wv;  acc[10]+=c.z*wv; acc[11]+=c.w*wv;
      acc[12]+=d.x*wv; acc[13]+=d.y*wv; acc[14]+=d.z*wv; acc[15]+=d.w*wv;
    }
#pragma unroll
    for (int r=0;r<R;++r) hid[j*P+r] = fmaxf(acc[r],0.f);
  }
  __syncthreads();
  { // out col j2, 8 rows per thread
    int j2 = tid&127, r0 = (tid>>7)*8;
    float acc[8];
#pragma unroll
    for (int r=0;r<8;++r) acc[r]=0.f;
    for (int i=0;i<256;++i){
      float wv = W2[i*DOUTC + j2];
      const float4* xa = (const float4*)&hid[i*P + r0];
      float4 a=xa[0], b=xa[1];
      acc[0]+=a.x*wv; acc[1]+=a.y*wv; acc[2]+=a.z*wv; acc[3]+=a.w*wv;
      acc[4]+=b.x*wv; acc[5]+=b.y*wv; acc[6]+=b.z*wv; acc[7]+=b.w*wv;
    }
    float bj = bb2[j2];
#pragma unroll
    for (int r=0;r<8;++r)
      out[(size_t)(row0+r0+r)*DOUTC + j2] = hrow[r0+r][j2] + acc[r] + bj;
  }
}

extern "C" void kernel_launch(void* const* d_in, const int* in_sizes, int n_in,
                              void* d_out, int out_size, void* d_ws, size_t ws_size,
                              hipStream_t stream)
{
  const float* x     = (const float*)d_in[0];
  const int*   adj   = (const int*)  d_in[1];
  const float* ea    = (const float*)d_in[2];
  const float* ln1_g = (const float*)d_in[3];
  const float* ln1_b = (const float*)d_in[4];
  const float* Wp    = (const float*)d_in[5];
  const float* bp    = (const float*)d_in[6];
  const float* eln_g = (const float*)d_in[7];
  const float* eln_b = (const float*)d_in[8];
  const float* We1   = (const float*)d_in[9];
  const float* be1   = (const float*)d_in[10];
  const float* We2   = (const float*)d_in[11];
  const float* be2   = (const float*)d_in[12];
  const float* Wq    = (const float*)d_in[13];
  const float* Wk    = (const float*)d_in[14];
  const float* Wv    = (const float*)d_in[15];
  const float* ffW1  = (const float*)d_in[16];
  const float* ffb1  = (const float*)d_in[17];
  const float* ffW2  = (const float*)d_in[18];
  const float* ffb2  = (const float*)d_in[19];
  const float* ln2_g = (const float*)d_in[20];
  const float* ln2_b = (const float*)d_in[21];
  float* out = (float*)d_out;

  char* ws = (char*)d_ws;
  float*    xp  = (float*)(ws);                       // 2MB
  float*    ctx = (float*)(ws + ((size_t)2<<20));     // 2MB
  _Float16* Qh  = (_Float16*)(ws + ((size_t)4<<20));  // 1MB
  _Float16* Kh  = (_Float16*)(ws + ((size_t)5<<20));  // 1MB
  _Float16* Vh  = (_Float16*)(ws + ((size_t)6<<20));  // 1MB
  _Float16* ebf = (_Float16*)(ws + ((size_t)7<<20));  // 32MB [B,H,N,N] f16 (mask merged)

  k_proj<<<(BB*NN)/8, 128, 0, stream>>>(x, ln1_g, ln1_b, Wp, bp, Wq, Wk, Wv, xp, Qh, Kh, Vh);
  k_edge<<<BB*NN, 256, 0, stream>>>(ea, adj, eln_g, eln_b, We1, be1, We2, be2, ebf);
  k_attn<<<BB*HHC*8, 256, 0, stream>>>(Qh, Kh, Vh, ebf, ctx);
  k_ffn<<<(BB*NN)/16, 256, 0, stream>>>(xp, ctx, ln2_g, ln2_b, ffW1, ffb1, ffW2, ffb2, out);
}